// Round 25
// baseline (123.838 us; speedup 1.0000x reference)
//
#include <hip/hip_runtime.h>
#include <hip/hip_bf16.h>
#include <math.h>

#define HEADS 8
#define DIMH 40
#define BB 8
#define NN 4096
#define JJ 77
#define CDIM 768
#define INNER 320
#define NEGF (-3.4028234663852886e38f)

using bf16 = __hip_bfloat16;
using f32x4 = __attribute__((ext_vector_type(4))) float;
using bf16x8 = __attribute__((ext_vector_type(8))) short;
using ushort8 = __attribute__((ext_vector_type(8))) unsigned short;
using ushort4v = __attribute__((ext_vector_type(4))) unsigned short;

__device__ __forceinline__ unsigned short f2u(float f){
    bf16 t = __float2bfloat16(f);
    return *reinterpret_cast<unsigned short*>(&t);
}
__device__ __forceinline__ float u2f(unsigned short u){
    unsigned int w = ((unsigned int)u) << 16;
    return __uint_as_float(w);
}

// ---------------- unified weight prep + counter init
__global__ __launch_bounds__(256) void prep_weights(const float* __restrict__ Wq,
                                                    const float* __restrict__ Wo,
                                                    const float* __restrict__ Wk,
                                                    const float* __restrict__ Wv,
                                                    unsigned short* __restrict__ WqT,
                                                    unsigned short* __restrict__ WoT,
                                                    unsigned short* __restrict__ WkvT,
                                                    int* __restrict__ counter){
    if(blockIdx.x==0 && threadIdx.x==0) *counter = 0;   // visible before gemm_q_stats launches
    __shared__ float tile[32][33];
    int blk = blockIdx.x;
    int tx = threadIdx.x & 31, ty = threadIdx.x >> 5;
    if(blk < 200){
        const float* in = (blk<100)? Wq : Wo;
        unsigned short* out = (blk<100)? WqT : WoT;
        int base = (blk<100)? blk : blk-100;
        int bx = base%10, by = base/10;
        int c0 = bx*32, r0 = by*32;
        #pragma unroll
        for(int i=0;i<32;i+=8) tile[ty+i][tx] = in[(size_t)(r0+ty+i)*320 + c0+tx];
        __syncthreads();
        #pragma unroll
        for(int i=0;i<32;i+=8) out[(size_t)(c0+ty+i)*320 + r0+tx] = f2u(tile[tx][ty+i]);
    } else {
        int local = blk-200;              // 0..479
        int nt = local%20, kt = local/20;
        int n0 = nt*32, k0 = kt*32;
        const float* in = (n0<320)? Wk : Wv;
        int nc0 = (n0<320)? n0 : n0-320;
        #pragma unroll
        for(int i=0;i<32;i+=8) tile[ty+i][tx] = in[(size_t)(k0+ty+i)*320 + nc0+tx];
        __syncthreads();
        #pragma unroll
        for(int i=0;i<32;i+=8) WkvT[(size_t)(n0+ty+i)*768 + k0+tx] = f2u(tile[tx][ty+i]);
    }
}

// ---------------- K/V projection as MFMA GEMM with A-prefetch
__global__ __launch_bounds__(256) void proj_kv_mfma(const float* __restrict__ embs,
                                                    const unsigned short* __restrict__ WkvT,
                                                    unsigned short* __restrict__ kws,
                                                    unsigned short* __restrict__ vt){
    __shared__ unsigned short As[64][40];
    __shared__ unsigned short Bs[64][40];
    int t = threadIdx.x;
    int bm = blockIdx.x % 10;
    int bn = blockIdx.x / 10;
    int row0 = bm*64, col0 = bn*64;
    int wave=t>>6, lane=t&63, l15=lane&15, lk=lane>>4;

    f32x4 acc[4];
    #pragma unroll
    for(int nf=0;nf<4;nf++) acc[nf]=(f32x4){0.f,0.f,0.f,0.f};

    int r0s[2], kks[2]; bool val[2];
    float4 vreg[2];
    #pragma unroll
    for(int p=0;p<2;p++){
        int li = (p*256+t)*4; r0s[p] = li>>5; kks[p] = li&31;
        val[p] = (row0 + r0s[p]) < 616;
        vreg[p] = val[p] ? *(const float4*)&embs[(size_t)(row0+r0s[p])*768 + kks[p]]
                         : (float4){0.f,0.f,0.f,0.f};
    }

    for(int k0=0;k0<768;k0+=32){
        #pragma unroll
        for(int p=0;p<2;p++){
            float4 v = vreg[p];
            ushort4v u; u.x=f2u(v.x); u.y=f2u(v.y); u.z=f2u(v.z); u.w=f2u(v.w);
            *(ushort4v*)&As[r0s[p]][kks[p]] = u;
        }
        {
            int nn = t>>2, kk = (t&3)*8;
            *(ushort8*)&Bs[nn][kk] = *(const ushort8*)&WkvT[(size_t)(col0+nn)*768 + k0+kk];
        }
        __syncthreads();
        if(k0 < 736){
            #pragma unroll
            for(int p=0;p<2;p++){
                vreg[p] = val[p] ? *(const float4*)&embs[(size_t)(row0+r0s[p])*768 + (k0+32) + kks[p]]
                                 : (float4){0.f,0.f,0.f,0.f};
            }
        }
        bf16x8 aF = *(const bf16x8*)&As[wave*16+l15][lk*8];
        #pragma unroll
        for(int nf=0;nf<4;nf++){
            bf16x8 bF = *(const bf16x8*)&Bs[nf*16+l15][lk*8];
            acc[nf] = __builtin_amdgcn_mfma_f32_16x16x32_bf16(aF,bF,acc[nf],0,0,0);
        }
        __syncthreads();
    }
    #pragma unroll
    for(int nf=0;nf<4;nf++){
        int col = col0 + nf*16 + l15;
        #pragma unroll
        for(int r=0;r<4;r++){
            int m = row0 + wave*16 + lk*4 + r;
            if(m < 616){
                int b = m/77, j = m - 77*b;
                unsigned short val2 = f2u(acc[nf][r]);
                if(col < 320){
                    int h = col/40, d = col - 40*h;
                    kws[(((size_t)b*HEADS+h)*JJ + j)*DIMH + d] = val2;
                } else {
                    int c2 = col-320; int h = c2/40, d = c2 - 40*h;
                    size_t vbase = (((size_t)b*HEADS+h)*DIMH + d)*80;
                    vt[vbase + j] = val2;
                    if(j==76){ vt[vbase+77]=0; vt[vbase+78]=0; vt[vbase+79]=0; }
                }
            }
        }
    }
}

// ---------------- fused q-projection + global stats + LAST-BLOCK finalize
__global__ __launch_bounds__(256) void gemm_q_stats(const float* __restrict__ x,
                                                    const unsigned short* __restrict__ WqT,
                                                    const unsigned short* __restrict__ kws,
                                                    const int* __restrict__ ct,
                                                    const int* __restrict__ gpm,
                                                    const float* __restrict__ strength,
                                                    unsigned short* __restrict__ qh,
                                                    float2* __restrict__ partials,
                                                    int* __restrict__ counter,
                                                    float* __restrict__ kmT,
                                                    float* __restrict__ adT,
                                                    float* __restrict__ gmT){
    __shared__ unsigned short SH[256*84];      // 43,008 B pool
    unsigned short* As = SH;
    unsigned short* Bs = SH + 256*40;
    int t = threadIdx.x;
    int g  = blockIdx.x >> 5;
    int w  = blockIdx.x & 31;
    int bn = w >> 3;
    int bm = g*8 + (w & 7);
    int row0 = bm*256, col0 = bn*80;
    int wave = t>>6, lane = t&63;
    int l15 = lane&15, lk = lane>>4;
    int b = row0 >> 12;
    bf16x8 zb = {0,0,0,0,0,0,0,0};

    f32x4 acc[4][5];
    #pragma unroll
    for(int i=0;i<4;i++)
        #pragma unroll
        for(int j=0;j<5;j++) acc[i][j] = (f32x4){0.f,0.f,0.f,0.f};

    float4 vreg[8];
    #pragma unroll
    for(int p=0;p<8;p++){
        int li = (p*256+t)*4; int r = li>>5, kk = li&31;
        vreg[p] = *(const float4*)&x[(size_t)(row0+r)*320 + kk];
    }

    for(int k0=0;k0<320;k0+=32){
        #pragma unroll
        for(int p=0;p<8;p++){
            int li = (p*256+t)*4; int r = li>>5, kk = li&31;
            float4 v = vreg[p];
            ushort4v u; u.x=f2u(v.x); u.y=f2u(v.y); u.z=f2u(v.z); u.w=f2u(v.w);
            *(ushort4v*)&As[r*40+kk] = u;
        }
        #pragma unroll
        for(int p=0;p<2;p++){
            int idx = p*256+t;
            if(idx < 320){
                int nn = idx>>2, kk = (idx&3)*8;
                *(ushort8*)&Bs[nn*40+kk] = *(const ushort8*)&WqT[(size_t)(col0+nn)*320 + k0+kk];
            }
        }
        __syncthreads();
        if(k0 < 288){
            #pragma unroll
            for(int p=0;p<8;p++){
                int li = (p*256+t)*4; int r = li>>5, kk = li&31;
                vreg[p] = *(const float4*)&x[(size_t)(row0+r)*320 + (k0+32) + kk];
            }
        }
        bf16x8 a[4], bb[5];
        #pragma unroll
        for(int mf=0;mf<4;mf++) a[mf] = *(const bf16x8*)&As[(wave*64+mf*16+l15)*40 + lk*8];
        #pragma unroll
        for(int nf=0;nf<5;nf++) bb[nf] = *(const bf16x8*)&Bs[(nf*16+l15)*40 + lk*8];
        #pragma unroll
        for(int mf=0;mf<4;mf++)
            #pragma unroll
            for(int nf=0;nf<5;nf++)
                acc[mf][nf] = __builtin_amdgcn_mfma_f32_16x16x32_bf16(a[mf], bb[nf], acc[mf][nf], 0,0,0);
        __syncthreads();
    }
    #pragma unroll
    for(int mf=0;mf<4;mf++)
        #pragma unroll
        for(int nf=0;nf<5;nf++){
            int col = col0 + nf*16 + l15;
            int h = col/40, d = col - 40*h;
            int lcol = nf*16 + l15;
            #pragma unroll
            for(int r=0;r<4;r++){
                int lrow = wave*64 + mf*16 + lk*4 + r;
                int n = (row0 & 4095) + lrow;
                unsigned short v = f2u(acc[mf][nf][r]);
                qh[(((size_t)(b*8+h))*NN + n)*DIMH + d] = v;
                SH[lrow*84 + lcol] = v;
            }
        }
    __syncthreads();
    float s1=0.f, s2=0.f;
    #pragma unroll
    for(int h2=0;h2<2;h2++){
        int bh = b*8 + bn*2 + h2;
        bool kv[5]; bf16x8 bK0[5], bK1[5];
        #pragma unroll
        for(int jt=0;jt<5;jt++){
            int j = jt*16+l15;
            kv[jt] = (j<JJ) && (ct[b*JJ+j]>=0);
            bK0[jt] = (j<JJ) ? *(const bf16x8*)&kws[((size_t)bh*JJ+j)*DIMH + lk*8] : zb;
            bK1[jt] = (j<JJ && lk==0) ? *(const bf16x8*)&kws[((size_t)bh*JJ+j)*DIMH + 32] : zb;
        }
        #pragma unroll
        for(int mfq=0;mfq<4;mfq++){
            int wq = wave*64 + mfq*16;
            bf16x8 aF0 = *(const bf16x8*)&SH[(wq+l15)*84 + h2*40 + lk*8];
            bf16x8 aF1 = (lk==0) ? *(const bf16x8*)&SH[(wq+l15)*84 + h2*40 + 32] : zb;
            f32x4 sacc[5];
            #pragma unroll
            for(int jt=0;jt<5;jt++) sacc[jt]=(f32x4){0.f,0.f,0.f,0.f};
            #pragma unroll
            for(int jt=0;jt<5;jt++){
                sacc[jt] = __builtin_amdgcn_mfma_f32_16x16x32_bf16(aF0,bK0[jt],sacc[jt],0,0,0);
                sacc[jt] = __builtin_amdgcn_mfma_f32_16x16x32_bf16(aF1,bK1[jt],sacc[jt],0,0,0);
            }
            #pragma unroll
            for(int jt=0;jt<5;jt++){
                if(kv[jt]){
                    #pragma unroll
                    for(int r=0;r<4;r++){ float v=sacc[jt][r]; s1+=v; s2+=v*v; }
                }
            }
        }
    }
    #pragma unroll
    for(int off=32;off>0;off>>=1){ s1 += __shfl_down(s1,off); s2 += __shfl_down(s2,off); }
    __shared__ float sa[4], sb[4];
    __shared__ int sdone;
    if(lane==0){ sa[wave]=s1; sb[wave]=s2; }
    __syncthreads();
    if(t==0){
        partials[blockIdx.x] = make_float2(sa[0]+sa[1]+sa[2]+sa[3],
                                           sb[0]+sb[1]+sb[2]+sb[3]);
        __threadfence();                       // release: partials visible device-wide
        sdone = (atomicAdd(counter,1) == 511);
    }
    __syncthreads();
    if(!sdone) return;
    // ---- last block: finalize (identical math to the old finalize_kernel) ----
    __threadfence();                           // acquire: see all partials
    __shared__ int sflag2, scnt2;
    if(t==0){ sflag2=0; scnt2=0; }
    __syncthreads();
    int lflag=0, lcnt=0;
    for(int i=t;i<154;i+=256){ int gg = gpm[i]; if(gg!=0 && gg!=1) lflag=1; }
    for(int i=t;i<BB*JJ;i+=256){ if(ct[i]>=0) lcnt++; }
    if(lflag) atomicOr(&sflag2,1);
    atomicAdd(&scnt2,lcnt);
    double d1=0.0, d2=0.0;
    for(int i=t;i<512;i+=256){
        float2 p = partials[i];
        d1 += (double)p.x; d2 += (double)p.y;
    }
    #pragma unroll
    for(int off=32;off>0;off>>=1){ d1 += __shfl_down(d1,off); d2 += __shfl_down(d2,off); }
    __shared__ double da[4], db[4];
    __shared__ float s_simstd;
    int w2 = t>>6;
    if(lane==0){ da[w2]=d1; db[w2]=d2; }
    __syncthreads();
    if(t==0){
        double S1 = da[0]+da[1]+da[2]+da[3];
        double S2 = db[0]+db[1]+db[2]+db[3];
        double cnt = (double)scnt2 * HEADS * NN;
        double var = (S2 - S1*S1/cnt)/(cnt-1.0);
        s_simstd = (float)sqrt(var);
    }
    __syncthreads();
    float c = s_simstd * strength[0];
    int gflag = sflag2;
    for(int i=t;i<BB*80;i+=256){
        int bb2 = i/80, j = i-80*bb2;
        int kvv=0, gv=0;
        if(j<JJ){
            kvv = ct[bb2*JJ+j]>=0;
            gv = gflag ? (((const unsigned char*)gpm)[bb2*JJ+j]!=0) : (gpm[bb2*JJ+j]!=0);
        }
        kmT[i] = (j<JJ && kvv)?1.f:0.f;
        adT[i] = ((j<JJ && kvv)?0.f:NEGF) + ((j<JJ && gv)?0.f:NEGF);
        gmT[i] = (j<JJ && gv)? c : 0.f;
    }
}

// ---------------- MFMA GEMM (output projection): 128x64, XCD-aware, A-prefetch
template<int A_MODE, int C_MODE>
__global__ __launch_bounds__(256) void gemm_mfma(const void* __restrict__ A,
                                                 const unsigned short* __restrict__ Bt,
                                                 const float* __restrict__ bias,
                                                 void* __restrict__ C){
    __shared__ unsigned short As[128][40];
    __shared__ unsigned short Bs[64][40];
    int t = threadIdx.x;
    int g  = blockIdx.x / 40;
    int w  = blockIdx.x % 40;
    int bn = w >> 3;
    int bm = g*8 + (w & 7);
    int row0 = bm*128, col0 = bn*64;
    int wave = t>>6, lane = t&63;
    int l15 = lane&15, lk = lane>>4;

    f32x4 acc[2][4];
    #pragma unroll
    for(int i=0;i<2;i++)
        #pragma unroll
        for(int j=0;j<4;j++) acc[i][j] = (f32x4){0.f,0.f,0.f,0.f};

    const unsigned short* Ab = (const unsigned short*)A;
    ushort8 areg[2];
    int rr[2], kk0[2];
    #pragma unroll
    for(int p=0;p<2;p++){
        int li = (p*256+t)*8; rr[p] = li>>5; kk0[p] = li&31;
        int m = row0+rr[p]; int k = kk0[p];
        int bq = m>>12, n = m&4095;
        int h = k/40, d = k-40*h;
        areg[p] = *(const ushort8*)&Ab[(((size_t)(bq*8+h))*NN + n)*DIMH + d];
    }

    for(int k0=0;k0<320;k0+=32){
        #pragma unroll
        for(int p=0;p<2;p++) *(ushort8*)&As[rr[p]][kk0[p]] = areg[p];
        {
            int nn = t>>2, kk = (t&3)*8;
            *(ushort8*)&Bs[nn][kk] = *(const ushort8*)&Bt[(size_t)(col0+nn)*320 + k0+kk];
        }
        __syncthreads();
        if(k0 < 288){
            #pragma unroll
            for(int p=0;p<2;p++){
                int m = row0+rr[p]; int k = k0+32+kk0[p];
                int bq = m>>12, n = m&4095;
                int h = k/40, d = k-40*h;
                areg[p] = *(const ushort8*)&Ab[(((size_t)(bq*8+h))*NN + n)*DIMH + d];
            }
        }
        bf16x8 a[2], bfr[4];
        #pragma unroll
        for(int mf=0;mf<2;mf++) a[mf] = *(const bf16x8*)&As[wave*32+mf*16+l15][lk*8];
        #pragma unroll
        for(int nf=0;nf<4;nf++) bfr[nf] = *(const bf16x8*)&Bs[nf*16+l15][lk*8];
        #pragma unroll
        for(int mf=0;mf<2;mf++)
            #pragma unroll
            for(int nf=0;nf<4;nf++)
                acc[mf][nf] = __builtin_amdgcn_mfma_f32_16x16x32_bf16(a[mf], bfr[nf], acc[mf][nf], 0,0,0);
        __syncthreads();
    }
    if(C_MODE==1){
        float* Cf = (float*)C;
        float bv[4];
        #pragma unroll
        for(int nf=0;nf<4;nf++) bv[nf] = bias[col0+nf*16+l15];
        #pragma unroll
        for(int mf=0;mf<2;mf++)
            #pragma unroll
            for(int nf=0;nf<4;nf++){
                int col = col0+nf*16+l15;
                #pragma unroll
                for(int r=0;r<4;r++){
                    int m = row0+wave*32+mf*16+lk*4+r;
                    Cf[(size_t)m*320+col] = acc[mf][nf][r] + bv[nf];
                }
            }
    }
}

// ---------------- attention (round-15 body; grid swizzled: x=n-tiles, y=head-pairs)
__global__ __launch_bounds__(256) void attn_mfma(unsigned short* qh,
                                                 const unsigned short* __restrict__ kws,
                                                 const unsigned short* __restrict__ vt,
                                                 const float* __restrict__ cam,
                                                 const float* __restrict__ kmT,
                                                 const float* __restrict__ adT,
                                                 const float* __restrict__ gmT){
    int bp = blockIdx.y;
    int b = bp>>2, hp = bp&3;
    int bh0 = b*8 + hp*2;
    __shared__ unsigned short camS[64][80];
    __shared__ unsigned short P[64][104];
    int t = threadIdx.x;
    int wave=t>>6, lane=t&63, l15=lane&15, lk=lane>>4;
    int wq0 = wave*16;
    bf16x8 zb = {0,0,0,0,0,0,0,0};
    ushort8 z8 = {0,0,0,0,0,0,0,0};
    int n0 = blockIdx.x*64;

    {
        const float* csrc = cam + ((size_t)b*NN + n0)*JJ;
        for(int idx=t; idx<64*JJ; idx+=256){
            int r = idx/JJ, j = idx - r*JJ;
            camS[r][j] = f2u(csrc[idx]);
        }
        for(int idx=t; idx<64*3; idx+=256){ int r=idx/3; camS[r][77+idx%3]=0; }
    }
    float km[5], gm[5], ad[5];
    #pragma unroll
    for(int jt=0;jt<5;jt++){
        int j = jt*16+l15;
        km[jt] = kmT[b*80+j]; ad[jt] = adT[b*80+j]; gm[jt] = gmT[b*80+j];
    }
    if(t<64){ *(ushort8*)&P[t][80]=z8; *(ushort8*)&P[t][88]=z8; *(ushort8*)&P[t][96]=z8; }
    __syncthreads();

    const float scale = 0.15811388300841897f;
    for(int h2=0;h2<2;h2++){
        int bh = bh0 + h2;
        size_t qrow = ((size_t)bh*NN + n0 + wq0 + l15)*DIMH;
        bf16x8 aF0 = *(const bf16x8*)&qh[qrow + lk*8];
        bf16x8 aF1 = (lk==0) ? *(const bf16x8*)&qh[qrow + 32] : zb;
        bf16x8 bK[2][5];
        #pragma unroll
        for(int ks=0;ks<2;ks++)
            #pragma unroll
            for(int jt=0;jt<5;jt++){
                int j = jt*16+l15;
                if(j<JJ && !(ks==1 && lk>=1))
                    bK[ks][jt] = *(const bf16x8*)&kws[((size_t)bh*JJ + j)*DIMH + ks*32 + lk*8];
                else bK[ks][jt] = zb;
            }
        bf16x8 bV[3][3];
        #pragma unroll
        for(int ks=0;ks<3;ks++)
            #pragma unroll
            for(int nt=0;nt<3;nt++){
                int d = nt*16+l15;
                if(d<DIMH && !(ks==2 && lk>=2))
                    bV[ks][nt] = *(const bf16x8*)&vt[((size_t)bh*DIMH + d)*80 + ks*32 + lk*8];
                else bV[ks][nt] = zb;
            }
        f32x4 sacc[5];
        #pragma unroll
        for(int jt=0;jt<5;jt++) sacc[jt]=(f32x4){0.f,0.f,0.f,0.f};
        #pragma unroll
        for(int jt=0;jt<5;jt++){
            sacc[jt] = __builtin_amdgcn_mfma_f32_16x16x32_bf16(aF0,bK[0][jt],sacc[jt],0,0,0);
            sacc[jt] = __builtin_amdgcn_mfma_f32_16x16x32_bf16(aF1,bK[1][jt],sacc[jt],0,0,0);
        }
        float lo[5][4];
        #pragma unroll
        for(int jt=0;jt<5;jt++){
            int j = jt*16+l15;
            #pragma unroll
            for(int r=0;r<4;r++){
                float cvv = u2f(camS[wq0+4*lk+r][j]);
                lo[jt][r] = (sacc[jt][r]*km[jt] + cvv*gm[jt] + ad[jt])*scale;
            }
        }
        float dinv[4];
        #pragma unroll
        for(int r=0;r<4;r++){
            float m = lo[0][r];
            #pragma unroll
            for(int jt=1;jt<5;jt++) m = fmaxf(m, lo[jt][r]);
            #pragma unroll
            for(int msk=1;msk<16;msk<<=1) m = fmaxf(m, __shfl_xor(m,msk));
            float s=0.f;
            #pragma unroll
            for(int jt=0;jt<5;jt++){ float e=__expf(lo[jt][r]-m); lo[jt][r]=e; s+=e; }
            #pragma unroll
            for(int msk=1;msk<16;msk<<=1) s += __shfl_xor(s,msk);
            dinv[r]=1.f/s;
        }
        #pragma unroll
        for(int jt=0;jt<5;jt++){
            int j = jt*16+l15;
            #pragma unroll
            for(int r=0;r<4;r++) P[wq0+4*lk+r][j] = f2u(lo[jt][r]*dinv[r]);
        }
        __syncthreads();
        f32x4 oacc[3];
        #pragma unroll
        for(int nt=0;nt<3;nt++) oacc[nt]=(f32x4){0.f,0.f,0.f,0.f};
        #pragma unroll
        for(int ks=0;ks<3;ks++){
            bf16x8 aP = *(const bf16x8*)&P[wq0+l15][ks*32+lk*8];
            #pragma unroll
            for(int nt=0;nt<3;nt++)
                oacc[nt] = __builtin_amdgcn_mfma_f32_16x16x32_bf16(aP,bV[ks][nt],oacc[nt],0,0,0);
        }
        #pragma unroll
        for(int nt=0;nt<3;nt++){
            int d = nt*16+l15;
            #pragma unroll
            for(int r=0;r<4;r++){
                unsigned short ush = f2u(oacc[nt][r]);
                int other = __shfl_xor((int)ush, 1);
                if((l15&1)==0 && d<DIMH){
                    unsigned int word = (unsigned int)ush | (((unsigned int)(unsigned short)other)<<16);
                    int row = n0 + wq0 + 4*lk + r;
                    *(unsigned int*)&qh[((size_t)bh*NN + row)*DIMH + d] = word;
                }
            }
        }
        __syncthreads();
    }
}

extern "C" void kernel_launch(void* const* d_in, const int* in_sizes, int n_in,
                              void* d_out, int out_size, void* d_ws, size_t ws_size,
                              hipStream_t stream) {
    const float* x        = (const float*)d_in[0];
    const float* embs     = (const float*)d_in[1];
    const float* Wq       = (const float*)d_in[2];
    const float* Wk       = (const float*)d_in[3];
    const float* Wv       = (const float*)d_in[4];
    const float* Wo       = (const float*)d_in[5];
    const float* bo       = (const float*)d_in[6];
    const float* cam      = (const float*)d_in[7];
    const float* strength = (const float*)d_in[8];
    const int*  ct       = (const int*)d_in[9];
    const int*  gpm      = (const int*)d_in[10];

    char* ws = (char*)d_ws;
    unsigned short* qh   = (unsigned short*)ws;                    // 20,971,520 B (head-major)
    unsigned short* kws  = (unsigned short*)(ws + 20971520);       // 394,240
    unsigned short* vt   = (unsigned short*)(ws + 21365760);       // 409,600
    unsigned short* WqT  = (unsigned short*)(ws + 21775360);       // 204,800
    unsigned short* WoT  = (unsigned short*)(ws + 21980160);       // 204,800
    unsigned short* WkvT = (unsigned short*)(ws + 22184960);       // 983,040
    float2* partials = (float2*)(ws + 23168000);                   // 4,096
    float* kmT = (float*)(ws + 23173120);                          // 2,560
    float* adT = (float*)(ws + 23175680);                          // 2,560
    float* gmT = (float*)(ws + 23178240);                          // 2,560
    int* counter = (int*)(ws + 23180800);                          // 4

    prep_weights<<<680,256,0,stream>>>(Wq,Wo,Wk,Wv,WqT,WoT,WkvT,counter);
    proj_kv_mfma<<<100,256,0,stream>>>(embs,WkvT,kws,vt);
    gemm_q_stats<<<512,256,0,stream>>>(x,WqT,kws,ct,gpm,strength,qh,partials,counter,kmT,adT,gmT);
    attn_mfma<<<dim3(64,32),256,0,stream>>>(qh,kws,vt,cam,kmT,adT,gmT);
    gemm_mfma<2,1><<<1280,256,0,stream>>>(qh,WoT,bo,d_out);
}

// Round 26
// 115.415 us; speedup vs baseline: 1.0730x; 1.0730x over previous
//
#include <hip/hip_runtime.h>
#include <hip/hip_bf16.h>
#include <math.h>

#define HEADS 8
#define DIMH 40
#define BB 8
#define NN 4096
#define JJ 77
#define CDIM 768
#define INNER 320
#define NEGF (-3.4028234663852886e38f)

using bf16 = __hip_bfloat16;
using f32x4 = __attribute__((ext_vector_type(4))) float;
using bf16x8 = __attribute__((ext_vector_type(8))) short;
using ushort8 = __attribute__((ext_vector_type(8))) unsigned short;
using ushort4v = __attribute__((ext_vector_type(4))) unsigned short;

__device__ __forceinline__ unsigned short f2u(float f){
    bf16 t = __float2bfloat16(f);
    return *reinterpret_cast<unsigned short*>(&t);
}
__device__ __forceinline__ float u2f(unsigned short u){
    unsigned int w = ((unsigned int)u) << 16;
    return __uint_as_float(w);
}

// ---------------- unified weight prep: WqT, WoT (320x320 transpose) + WkvT[640][768]
__global__ __launch_bounds__(256) void prep_weights(const float* __restrict__ Wq,
                                                    const float* __restrict__ Wo,
                                                    const float* __restrict__ Wk,
                                                    const float* __restrict__ Wv,
                                                    unsigned short* __restrict__ WqT,
                                                    unsigned short* __restrict__ WoT,
                                                    unsigned short* __restrict__ WkvT){
    __shared__ float tile[32][33];
    int blk = blockIdx.x;
    int tx = threadIdx.x & 31, ty = threadIdx.x >> 5;
    if(blk < 200){
        const float* in = (blk<100)? Wq : Wo;
        unsigned short* out = (blk<100)? WqT : WoT;
        int base = (blk<100)? blk : blk-100;
        int bx = base%10, by = base/10;
        int c0 = bx*32, r0 = by*32;
        #pragma unroll
        for(int i=0;i<32;i+=8) tile[ty+i][tx] = in[(size_t)(r0+ty+i)*320 + c0+tx];
        __syncthreads();
        #pragma unroll
        for(int i=0;i<32;i+=8) out[(size_t)(c0+ty+i)*320 + r0+tx] = f2u(tile[tx][ty+i]);
    } else {
        int local = blk-200;              // 0..479
        int nt = local%20, kt = local/20;
        int n0 = nt*32, k0 = kt*32;
        const float* in = (n0<320)? Wk : Wv;
        int nc0 = (n0<320)? n0 : n0-320;
        #pragma unroll
        for(int i=0;i<32;i+=8) tile[ty+i][tx] = in[(size_t)(k0+ty+i)*320 + nc0+tx];
        __syncthreads();
        #pragma unroll
        for(int i=0;i<32;i+=8) WkvT[(size_t)(n0+ty+i)*768 + k0+tx] = f2u(tile[tx][ty+i]);
    }
}

// ---------------- K/V projection as MFMA GEMM with A-prefetch
__global__ __launch_bounds__(256) void proj_kv_mfma(const float* __restrict__ embs,
                                                    const unsigned short* __restrict__ WkvT,
                                                    unsigned short* __restrict__ kws,
                                                    unsigned short* __restrict__ vt){
    __shared__ unsigned short As[64][40];
    __shared__ unsigned short Bs[64][40];
    int t = threadIdx.x;
    int bm = blockIdx.x % 10;
    int bn = blockIdx.x / 10;
    int row0 = bm*64, col0 = bn*64;
    int wave=t>>6, lane=t&63, l15=lane&15, lk=lane>>4;

    f32x4 acc[4];
    #pragma unroll
    for(int nf=0;nf<4;nf++) acc[nf]=(f32x4){0.f,0.f,0.f,0.f};

    // per-thread A-load geometry (k-invariant)
    int r0s[2], kks[2]; bool val[2];
    float4 vreg[2];
    #pragma unroll
    for(int p=0;p<2;p++){
        int li = (p*256+t)*4; r0s[p] = li>>5; kks[p] = li&31;
        val[p] = (row0 + r0s[p]) < 616;
        vreg[p] = val[p] ? *(const float4*)&embs[(size_t)(row0+r0s[p])*768 + kks[p]]
                         : (float4){0.f,0.f,0.f,0.f};
    }

    for(int k0=0;k0<768;k0+=32){
        #pragma unroll
        for(int p=0;p<2;p++){
            float4 v = vreg[p];
            ushort4v u; u.x=f2u(v.x); u.y=f2u(v.y); u.z=f2u(v.z); u.w=f2u(v.w);
            *(ushort4v*)&As[r0s[p]][kks[p]] = u;
        }
        {
            int nn = t>>2, kk = (t&3)*8;
            *(ushort8*)&Bs[nn][kk] = *(const ushort8*)&WkvT[(size_t)(col0+nn)*768 + k0+kk];
        }
        __syncthreads();
        if(k0 < 736){
            #pragma unroll
            for(int p=0;p<2;p++){
                vreg[p] = val[p] ? *(const float4*)&embs[(size_t)(row0+r0s[p])*768 + (k0+32) + kks[p]]
                                 : (float4){0.f,0.f,0.f,0.f};
            }
        }
        bf16x8 aF = *(const bf16x8*)&As[wave*16+l15][lk*8];
        #pragma unroll
        for(int nf=0;nf<4;nf++){
            bf16x8 bF = *(const bf16x8*)&Bs[nf*16+l15][lk*8];
            acc[nf] = __builtin_amdgcn_mfma_f32_16x16x32_bf16(aF,bF,acc[nf],0,0,0);
        }
        __syncthreads();
    }
    #pragma unroll
    for(int nf=0;nf<4;nf++){
        int col = col0 + nf*16 + l15;
        #pragma unroll
        for(int r=0;r<4;r++){
            int m = row0 + wave*16 + lk*4 + r;
            if(m < 616){
                int b = m/77, j = m - 77*b;
                unsigned short val2 = f2u(acc[nf][r]);
                if(col < 320){
                    int h = col/40, d = col - 40*h;
                    kws[(((size_t)b*HEADS+h)*JJ + j)*DIMH + d] = val2;
                } else {
                    int c2 = col-320; int h = c2/40, d = c2 - 40*h;
                    size_t vbase = (((size_t)b*HEADS+h)*DIMH + d)*80;
                    vt[vbase + j] = val2;
                    if(j==76){ vt[vbase+77]=0; vt[vbase+78]=0; vt[vbase+79]=0; }
                }
            }
        }
    }
}

// ---------------- fused q-projection + global stats: 256x80 tile, grid 512
// XCD-aware decode; stride-84 stash; REGISTER-PREFETCH of next x-tile
__global__ __launch_bounds__(256) void gemm_q_stats(const float* __restrict__ x,
                                                    const unsigned short* __restrict__ WqT,
                                                    const unsigned short* __restrict__ kws,
                                                    const int* __restrict__ ct,
                                                    unsigned short* __restrict__ qh,
                                                    float2* __restrict__ partials){
    __shared__ unsigned short SH[256*84];      // 43,008 B pool
    unsigned short* As = SH;
    unsigned short* Bs = SH + 256*40;
    int t = threadIdx.x;
    int g  = blockIdx.x >> 5;
    int w  = blockIdx.x & 31;
    int bn = w >> 3;
    int bm = g*8 + (w & 7);
    int row0 = bm*256, col0 = bn*80;
    int wave = t>>6, lane = t&63;
    int l15 = lane&15, lk = lane>>4;
    int b = row0 >> 12;
    bf16x8 zb = {0,0,0,0,0,0,0,0};

    f32x4 acc[4][5];
    #pragma unroll
    for(int i=0;i<4;i++)
        #pragma unroll
        for(int j=0;j<5;j++) acc[i][j] = (f32x4){0.f,0.f,0.f,0.f};

    float4 vreg[8];
    #pragma unroll
    for(int p=0;p<8;p++){
        int li = (p*256+t)*4; int r = li>>5, kk = li&31;
        vreg[p] = *(const float4*)&x[(size_t)(row0+r)*320 + kk];
    }

    for(int k0=0;k0<320;k0+=32){
        #pragma unroll
        for(int p=0;p<8;p++){
            int li = (p*256+t)*4; int r = li>>5, kk = li&31;
            float4 v = vreg[p];
            ushort4v u; u.x=f2u(v.x); u.y=f2u(v.y); u.z=f2u(v.z); u.w=f2u(v.w);
            *(ushort4v*)&As[r*40+kk] = u;
        }
        #pragma unroll
        for(int p=0;p<2;p++){
            int idx = p*256+t;
            if(idx < 320){
                int nn = idx>>2, kk = (idx&3)*8;
                *(ushort8*)&Bs[nn*40+kk] = *(const ushort8*)&WqT[(size_t)(col0+nn)*320 + k0+kk];
            }
        }
        __syncthreads();
        if(k0 < 288){
            #pragma unroll
            for(int p=0;p<8;p++){
                int li = (p*256+t)*4; int r = li>>5, kk = li&31;
                vreg[p] = *(const float4*)&x[(size_t)(row0+r)*320 + (k0+32) + kk];
            }
        }
        bf16x8 a[4], bb[5];
        #pragma unroll
        for(int mf=0;mf<4;mf++) a[mf] = *(const bf16x8*)&As[(wave*64+mf*16+l15)*40 + lk*8];
        #pragma unroll
        for(int nf=0;nf<5;nf++) bb[nf] = *(const bf16x8*)&Bs[(nf*16+l15)*40 + lk*8];
        #pragma unroll
        for(int mf=0;mf<4;mf++)
            #pragma unroll
            for(int nf=0;nf<5;nf++)
                acc[mf][nf] = __builtin_amdgcn_mfma_f32_16x16x32_bf16(a[mf], bb[nf], acc[mf][nf], 0,0,0);
        __syncthreads();
    }
    #pragma unroll
    for(int mf=0;mf<4;mf++)
        #pragma unroll
        for(int nf=0;nf<5;nf++){
            int col = col0 + nf*16 + l15;
            int h = col/40, d = col - 40*h;
            int lcol = nf*16 + l15;
            #pragma unroll
            for(int r=0;r<4;r++){
                int lrow = wave*64 + mf*16 + lk*4 + r;
                int n = (row0 & 4095) + lrow;
                unsigned short v = f2u(acc[mf][nf][r]);
                qh[(((size_t)(b*8+h))*NN + n)*DIMH + d] = v;
                SH[lrow*84 + lcol] = v;
            }
        }
    __syncthreads();
    float s1=0.f, s2=0.f;
    #pragma unroll
    for(int h2=0;h2<2;h2++){
        int bh = b*8 + bn*2 + h2;
        bool kv[5]; bf16x8 bK0[5], bK1[5];
        #pragma unroll
        for(int jt=0;jt<5;jt++){
            int j = jt*16+l15;
            kv[jt] = (j<JJ) && (ct[b*JJ+j]>=0);
            bK0[jt] = (j<JJ) ? *(const bf16x8*)&kws[((size_t)bh*JJ+j)*DIMH + lk*8] : zb;
            bK1[jt] = (j<JJ && lk==0) ? *(const bf16x8*)&kws[((size_t)bh*JJ+j)*DIMH + 32] : zb;
        }
        #pragma unroll
        for(int mfq=0;mfq<4;mfq++){
            int wq = wave*64 + mfq*16;
            bf16x8 aF0 = *(const bf16x8*)&SH[(wq+l15)*84 + h2*40 + lk*8];
            bf16x8 aF1 = (lk==0) ? *(const bf16x8*)&SH[(wq+l15)*84 + h2*40 + 32] : zb;
            f32x4 sacc[5];
            #pragma unroll
            for(int jt=0;jt<5;jt++) sacc[jt]=(f32x4){0.f,0.f,0.f,0.f};
            #pragma unroll
            for(int jt=0;jt<5;jt++){
                sacc[jt] = __builtin_amdgcn_mfma_f32_16x16x32_bf16(aF0,bK0[jt],sacc[jt],0,0,0);
                sacc[jt] = __builtin_amdgcn_mfma_f32_16x16x32_bf16(aF1,bK1[jt],sacc[jt],0,0,0);
            }
            #pragma unroll
            for(int jt=0;jt<5;jt++){
                if(kv[jt]){
                    #pragma unroll
                    for(int r=0;r<4;r++){ float v=sacc[jt][r]; s1+=v; s2+=v*v; }
                }
            }
        }
    }
    #pragma unroll
    for(int off=32;off>0;off>>=1){ s1 += __shfl_down(s1,off); s2 += __shfl_down(s2,off); }
    __shared__ float sa[4], sb[4];
    if(lane==0){ sa[wave]=s1; sb[wave]=s2; }
    __syncthreads();
    if(t==0){
        partials[blockIdx.x] = make_float2(sa[0]+sa[1]+sa[2]+sa[3],
                                           sb[0]+sb[1]+sb[2]+sb[3]);
    }
}

// ---------------- finalize: reduce 512 partials -> simstd, build mask tables
__global__ __launch_bounds__(256) void finalize_kernel(const float2* __restrict__ partials,
                                                       const int* __restrict__ ct,
                                                       const int* __restrict__ gpm,
                                                       const float* __restrict__ strength,
                                                       float* __restrict__ kmT,
                                                       float* __restrict__ adT,
                                                       float* __restrict__ gmT){
    int t = threadIdx.x;
    __shared__ int sflag, scnt;
    if(t==0){ sflag=0; scnt=0; }
    __syncthreads();
    int lflag=0, lcnt=0;
    for(int i=t;i<154;i+=256){ int g = gpm[i]; if(g!=0 && g!=1) lflag=1; }
    for(int i=t;i<BB*JJ;i+=256){ if(ct[i]>=0) lcnt++; }
    if(lflag) atomicOr(&sflag,1);
    atomicAdd(&scnt,lcnt);
    double s1=0.0, s2=0.0;
    for(int i=t;i<512;i+=256){
        float2 p = partials[i];
        s1 += (double)p.x; s2 += (double)p.y;
    }
    #pragma unroll
    for(int off=32;off>0;off>>=1){ s1 += __shfl_down(s1,off); s2 += __shfl_down(s2,off); }
    __shared__ double da[4], db[4];
    __shared__ float s_simstd;
    int lane=t&63, w=t>>6;
    if(lane==0){ da[w]=s1; db[w]=s2; }
    __syncthreads();
    if(t==0){
        double S1 = da[0]+da[1]+da[2]+da[3];
        double S2 = db[0]+db[1]+db[2]+db[3];
        double cnt = (double)scnt * HEADS * NN;
        double var = (S2 - S1*S1/cnt)/(cnt-1.0);
        s_simstd = (float)sqrt(var);
    }
    __syncthreads();
    float c = s_simstd * strength[0];
    int gflag = sflag;
    for(int i=t;i<BB*80;i+=256){
        int b = i/80, j = i-80*b;
        int kvv=0, gv=0;
        if(j<JJ){
            kvv = ct[b*JJ+j]>=0;
            gv = gflag ? (((const unsigned char*)gpm)[b*JJ+j]!=0) : (gpm[b*JJ+j]!=0);
        }
        kmT[i] = (j<JJ && kvv)?1.f:0.f;
        adT[i] = ((j<JJ && kvv)?0.f:NEGF) + ((j<JJ && gv)?0.f:NEGF);
        gmT[i] = (j<JJ && gv)? c : 0.f;
    }
}

// ---------------- MFMA GEMM (output projection): 128x64, XCD-aware, A-prefetch
template<int A_MODE, int C_MODE>
__global__ __launch_bounds__(256) void gemm_mfma(const void* __restrict__ A,
                                                 const unsigned short* __restrict__ Bt,
                                                 const float* __restrict__ bias,
                                                 void* __restrict__ C){
    __shared__ unsigned short As[128][40];
    __shared__ unsigned short Bs[64][40];
    int t = threadIdx.x;
    int g  = blockIdx.x / 40;
    int w  = blockIdx.x % 40;
    int bn = w >> 3;
    int bm = g*8 + (w & 7);
    int row0 = bm*128, col0 = bn*64;
    int wave = t>>6, lane = t&63;
    int l15 = lane&15, lk = lane>>4;

    f32x4 acc[2][4];
    #pragma unroll
    for(int i=0;i<2;i++)
        #pragma unroll
        for(int j=0;j<4;j++) acc[i][j] = (f32x4){0.f,0.f,0.f,0.f};

    const unsigned short* Ab = (const unsigned short*)A;
    // prefetch geometry (A_MODE==2 path only used)
    ushort8 areg[2];
    int rr[2], kk0[2];
    #pragma unroll
    for(int p=0;p<2;p++){
        int li = (p*256+t)*8; rr[p] = li>>5; kk0[p] = li&31;
        int m = row0+rr[p]; int k = kk0[p];
        int bq = m>>12, n = m&4095;
        int h = k/40, d = k-40*h;
        areg[p] = *(const ushort8*)&Ab[(((size_t)(bq*8+h))*NN + n)*DIMH + d];
    }

    for(int k0=0;k0<320;k0+=32){
        #pragma unroll
        for(int p=0;p<2;p++) *(ushort8*)&As[rr[p]][kk0[p]] = areg[p];
        {
            int nn = t>>2, kk = (t&3)*8;
            *(ushort8*)&Bs[nn][kk] = *(const ushort8*)&Bt[(size_t)(col0+nn)*320 + k0+kk];
        }
        __syncthreads();
        if(k0 < 288){
            #pragma unroll
            for(int p=0;p<2;p++){
                int m = row0+rr[p]; int k = k0+32+kk0[p];
                int bq = m>>12, n = m&4095;
                int h = k/40, d = k-40*h;
                areg[p] = *(const ushort8*)&Ab[(((size_t)(bq*8+h))*NN + n)*DIMH + d];
            }
        }
        bf16x8 a[2], bfr[4];
        #pragma unroll
        for(int mf=0;mf<2;mf++) a[mf] = *(const bf16x8*)&As[wave*32+mf*16+l15][lk*8];
        #pragma unroll
        for(int nf=0;nf<4;nf++) bfr[nf] = *(const bf16x8*)&Bs[nf*16+l15][lk*8];
        #pragma unroll
        for(int mf=0;mf<2;mf++)
            #pragma unroll
            for(int nf=0;nf<4;nf++)
                acc[mf][nf] = __builtin_amdgcn_mfma_f32_16x16x32_bf16(a[mf], bfr[nf], acc[mf][nf], 0,0,0);
        __syncthreads();
    }
    if(C_MODE==1){
        float* Cf = (float*)C;
        float bv[4];
        #pragma unroll
        for(int nf=0;nf<4;nf++) bv[nf] = bias[col0+nf*16+l15];
        #pragma unroll
        for(int mf=0;mf<2;mf++)
            #pragma unroll
            for(int nf=0;nf<4;nf++){
                int col = col0+nf*16+l15;
                #pragma unroll
                for(int r=0;r<4;r++){
                    int m = row0+wave*32+mf*16+lk*4+r;
                    Cf[(size_t)m*320+col] = acc[mf][nf][r] + bv[nf];
                }
            }
    }
}

// ---------------- attention (round-15 body; grid swizzled: x=n-tiles, y=head-pairs)
__global__ __launch_bounds__(256) void attn_mfma(unsigned short* qh,
                                                 const unsigned short* __restrict__ kws,
                                                 const unsigned short* __restrict__ vt,
                                                 const float* __restrict__ cam,
                                                 const float* __restrict__ kmT,
                                                 const float* __restrict__ adT,
                                                 const float* __restrict__ gmT){
    int bp = blockIdx.y;
    int b = bp>>2, hp = bp&3;
    int bh0 = b*8 + hp*2;
    __shared__ unsigned short camS[64][80];
    __shared__ unsigned short P[64][104];
    int t = threadIdx.x;
    int wave=t>>6, lane=t&63, l15=lane&15, lk=lane>>4;
    int wq0 = wave*16;
    bf16x8 zb = {0,0,0,0,0,0,0,0};
    ushort8 z8 = {0,0,0,0,0,0,0,0};
    int n0 = blockIdx.x*64;

    {
        const float* csrc = cam + ((size_t)b*NN + n0)*JJ;
        for(int idx=t; idx<64*JJ; idx+=256){
            int r = idx/JJ, j = idx - r*JJ;
            camS[r][j] = f2u(csrc[idx]);
        }
        for(int idx=t; idx<64*3; idx+=256){ int r=idx/3; camS[r][77+idx%3]=0; }
    }
    float km[5], gm[5], ad[5];
    #pragma unroll
    for(int jt=0;jt<5;jt++){
        int j = jt*16+l15;
        km[jt] = kmT[b*80+j]; ad[jt] = adT[b*80+j]; gm[jt] = gmT[b*80+j];
    }
    if(t<64){ *(ushort8*)&P[t][80]=z8; *(ushort8*)&P[t][88]=z8; *(ushort8*)&P[t][96]=z8; }
    __syncthreads();

    const float scale = 0.15811388300841897f;
    for(int h2=0;h2<2;h2++){
        int bh = bh0 + h2;
        size_t qrow = ((size_t)bh*NN + n0 + wq0 + l15)*DIMH;
        bf16x8 aF0 = *(const bf16x8*)&qh[qrow + lk*8];
        bf16x8 aF1 = (lk==0) ? *(const bf16x8*)&qh[qrow + 32] : zb;
        bf16x8 bK[2][5];
        #pragma unroll
        for(int ks=0;ks<2;ks++)
            #pragma unroll
            for(int jt=0;jt<5;jt++){
                int j = jt*16+l15;
                if(j<JJ && !(ks==1 && lk>=1))
                    bK[ks][jt] = *(const bf16x8*)&kws[((size_t)bh*JJ + j)*DIMH + ks*32 + lk*8];
                else bK[ks][jt] = zb;
            }
        bf16x8 bV[3][3];
        #pragma unroll
        for(int ks=0;ks<3;ks++)
            #pragma unroll
            for(int nt=0;nt<3;nt++){
                int d = nt*16+l15;
                if(d<DIMH && !(ks==2 && lk>=2))
                    bV[ks][nt] = *(const bf16x8*)&vt[((size_t)bh*DIMH + d)*80 + ks*32 + lk*8];
                else bV[ks][nt] = zb;
            }
        f32x4 sacc[5];
        #pragma unroll
        for(int jt=0;jt<5;jt++) sacc[jt]=(f32x4){0.f,0.f,0.f,0.f};
        #pragma unroll
        for(int jt=0;jt<5;jt++){
            sacc[jt] = __builtin_amdgcn_mfma_f32_16x16x32_bf16(aF0,bK[0][jt],sacc[jt],0,0,0);
            sacc[jt] = __builtin_amdgcn_mfma_f32_16x16x32_bf16(aF1,bK[1][jt],sacc[jt],0,0,0);
        }
        float lo[5][4];
        #pragma unroll
        for(int jt=0;jt<5;jt++){
            int j = jt*16+l15;
            #pragma unroll
            for(int r=0;r<4;r++){
                float cvv = u2f(camS[wq0+4*lk+r][j]);
                lo[jt][r] = (sacc[jt][r]*km[jt] + cvv*gm[jt] + ad[jt])*scale;
            }
        }
        float dinv[4];
        #pragma unroll
        for(int r=0;r<4;r++){
            float m = lo[0][r];
            #pragma unroll
            for(int jt=1;jt<5;jt++) m = fmaxf(m, lo[jt][r]);
            #pragma unroll
            for(int msk=1;msk<16;msk<<=1) m = fmaxf(m, __shfl_xor(m,msk));
            float s=0.f;
            #pragma unroll
            for(int jt=0;jt<5;jt++){ float e=__expf(lo[jt][r]-m); lo[jt][r]=e; s+=e; }
            #pragma unroll
            for(int msk=1;msk<16;msk<<=1) s += __shfl_xor(s,msk);
            dinv[r]=1.f/s;
        }
        #pragma unroll
        for(int jt=0;jt<5;jt++){
            int j = jt*16+l15;
            #pragma unroll
            for(int r=0;r<4;r++) P[wq0+4*lk+r][j] = f2u(lo[jt][r]*dinv[r]);
        }
        __syncthreads();
        f32x4 oacc[3];
        #pragma unroll
        for(int nt=0;nt<3;nt++) oacc[nt]=(f32x4){0.f,0.f,0.f,0.f};
        #pragma unroll
        for(int ks=0;ks<3;ks++){
            bf16x8 aP = *(const bf16x8*)&P[wq0+l15][ks*32+lk*8];
            #pragma unroll
            for(int nt=0;nt<3;nt++)
                oacc[nt] = __builtin_amdgcn_mfma_f32_16x16x32_bf16(aP,bV[ks][nt],oacc[nt],0,0,0);
        }
        #pragma unroll
        for(int nt=0;nt<3;nt++){
            int d = nt*16+l15;
            #pragma unroll
            for(int r=0;r<4;r++){
                unsigned short ush = f2u(oacc[nt][r]);
                int other = __shfl_xor((int)ush, 1);
                if((l15&1)==0 && d<DIMH){
                    unsigned int word = (unsigned int)ush | (((unsigned int)(unsigned short)other)<<16);
                    int row = n0 + wq0 + 4*lk + r;
                    *(unsigned int*)&qh[((size_t)bh*NN + row)*DIMH + d] = word;
                }
            }
        }
        __syncthreads();
    }
}

extern "C" void kernel_launch(void* const* d_in, const int* in_sizes, int n_in,
                              void* d_out, int out_size, void* d_ws, size_t ws_size,
                              hipStream_t stream) {
    const float* x        = (const float*)d_in[0];
    const float* embs     = (const float*)d_in[1];
    const float* Wq       = (const float*)d_in[2];
    const float* Wk       = (const float*)d_in[3];
    const float* Wv       = (const float*)d_in[4];
    const float* Wo       = (const float*)d_in[5];
    const float* bo       = (const float*)d_in[6];
    const float* cam      = (const float*)d_in[7];
    const float* strength = (const float*)d_in[8];
    const int*  ct       = (const int*)d_in[9];
    const int*  gpm      = (const int*)d_in[10];

    char* ws = (char*)d_ws;
    unsigned short* qh   = (unsigned short*)ws;                    // 20,971,520 B (head-major)
    unsigned short* kws  = (unsigned short*)(ws + 20971520);       // 394,240
    unsigned short* vt   = (unsigned short*)(ws + 21365760);       // 409,600
    unsigned short* WqT  = (unsigned short*)(ws + 21775360);       // 204,800
    unsigned short* WoT  = (unsigned short*)(ws + 21980160);       // 204,800
    unsigned short* WkvT = (unsigned short*)(ws + 22184960);       // 983,040
    float2* partials = (float2*)(ws + 23168000);                   // 4,096
    float* kmT = (float*)(ws + 23173120);                          // 2,560
    float* adT = (float*)(ws + 23175680);                          // 2,560
    float* gmT = (float*)(ws + 23178240);                          // 2,560

    prep_weights<<<680,256,0,stream>>>(Wq,Wo,Wk,Wv,WqT,WoT,WkvT);
    proj_kv_mfma<<<100,256,0,stream>>>(embs,WkvT,kws,vt);
    gemm_q_stats<<<512,256,0,stream>>>(x,WqT,kws,ct,qh,partials);
    finalize_kernel<<<1,256,0,stream>>>(partials,ct,gpm,strength,kmT,adT,gmT);
    attn_mfma<<<dim3(64,32),256,0,stream>>>(qh,kws,vt,cam,kmT,adT,gmT);
    gemm_mfma<2,1><<<1280,256,0,stream>>>(qh,WoT,bo,d_out);
}